// Round 1
// baseline (300.676 us; speedup 1.0000x reference)
//
#include <hip/hip_runtime.h>

#define S_LEN 2048
#define TOKEN_BITS 16
#define NHEAD 4
#define NPOS 12
#define VBITS 10
#define OBITS 12

__global__ __launch_bounds__(256) void pos_attn_kernel(
    const int*   __restrict__ tokens,        // (S,16) 0/1
    const int*   __restrict__ route_table,   // (H, 1<<24) 0/1
    const float* __restrict__ value_table,   // (H,16,1<<10)
    const float* __restrict__ output_table,  // (16,1<<12)
    const int*   __restrict__ conns_value,   // (H,16,10), values in [0,28)
    const int*   __restrict__ conns_out,     // (16,12), values in [0,64)
    float*       __restrict__ out)           // (S,16)
{
    const int s    = blockIdx.x;
    const int tid  = threadIdx.x;
    const int h    = tid >> 6;        // wave id = head
    const int lane = tid & 63;

    __shared__ unsigned short head_bits[NHEAD];

    // ---- 1. find j_first = argmax_j route_table[h, s<<12 | j] (first 1) ----
    const long long base = ((long long)h << 24) | ((long long)s << NPOS);
    int jf = -1;
    for (int j0 = 0; j0 < S_LEN; j0 += 64) {
        int v = route_table[base + j0 + lane];
        unsigned long long m = __ballot(v > 0);
        if (m) { jf = j0 + __ffsll((unsigned long long)m) - 1; break; }  // wave-uniform
    }

    // ---- 2. head output bits (16 bits per head) ----
    unsigned short my_bits = 0;
    if (jf >= 0) {
        // build vin word: bits 0..15 = tokens[jf], bits 16..27 = pos bits of jf
        int pred = 0;
        if (lane < TOKEN_BITS)              pred = tokens[jf * TOKEN_BITS + lane];
        else if (lane < TOKEN_BITS + NPOS)  pred = (jf >> (27 - lane)) & 1;  // pos_bits[m]=(j>>(11-m))&1, m=lane-16
        const unsigned long long vin = __ballot(pred != 0);

        int bit = 0;
        if (lane < TOKEN_BITS) {
            const int* cv = conns_value + (h * TOKEN_BITS + lane) * VBITS;
            int addr = 0;
#pragma unroll
            for (int b = 0; b < VBITS; ++b)
                addr |= (int)((vin >> cv[b]) & 1ULL) << (VBITS - 1 - b);   // MSB-first pack
            float val = value_table[(h * TOKEN_BITS + lane) * (1 << VBITS) + addr];
            bit = (val > 0.5f) ? 1 : 0;
        }
        unsigned long long bm = __ballot(bit);
        my_bits = (unsigned short)(bm & 0xFFFFu);
    }
    if (lane == 0) head_bits[h] = my_bits;
    __syncthreads();

    // ---- 3. output lookup: threads 0..15 each produce out[s, t] ----
    if (tid < TOKEN_BITS) {
        const unsigned long long cmask =
              (unsigned long long)head_bits[0]
            | ((unsigned long long)head_bits[1] << 16)
            | ((unsigned long long)head_bits[2] << 32)
            | ((unsigned long long)head_bits[3] << 48);
        const int* co = conns_out + tid * OBITS;
        int oaddr = 0;
#pragma unroll
        for (int b = 0; b < OBITS; ++b)
            oaddr |= (int)((cmask >> co[b]) & 1ULL) << (OBITS - 1 - b);    // MSB-first pack
        out[s * TOKEN_BITS + tid] = output_table[tid * (1 << OBITS) + oaddr];
    }
}

extern "C" void kernel_launch(void* const* d_in, const int* in_sizes, int n_in,
                              void* d_out, int out_size, void* d_ws, size_t ws_size,
                              hipStream_t stream) {
    const int*   tokens       = (const int*)  d_in[0];
    const int*   route_table  = (const int*)  d_in[1];
    const float* value_table  = (const float*)d_in[2];
    const float* output_table = (const float*)d_in[3];
    const int*   conns_value  = (const int*)  d_in[4];
    const int*   conns_out    = (const int*)  d_in[5];
    float*       out          = (float*)d_out;

    pos_attn_kernel<<<S_LEN, 256, 0, stream>>>(
        tokens, route_table, value_table, output_table, conns_value, conns_out, out);
}